// Round 14
// baseline (597.723 us; speedup 1.0000x reference)
//
#include <hip/hip_runtime.h>
#include <hip/hip_bf16.h>
#include <math.h>

#define NN 100000
#define CC 128
#define EE 1600000
#define EPT 8                    // edges per thread in edge-chunk kernels
#define FCHUNK (256 * EPT)       // 2048 edges per block
#define NCHUNKS ((EE + FCHUNK - 1) / FCHUNK)  // 782
#define NB_E NCHUNKS             // edge chunks
#define WB 512                   // nodes per bucket (power of 2)
#define WSHIFT 9
#define NBUCK ((NN + WB - 1) / WB)  // 196
#define NSLICE 8                 // feature slices (16 feats = 32B each); 1 per XCD
#define SL ((size_t)NN * 16)     // ushort elements per slice

typedef short  bf16x8 __attribute__((ext_vector_type(8)));
typedef float  f32x4  __attribute__((ext_vector_type(4)));
typedef unsigned short u16x8 __attribute__((ext_vector_type(8)));

#define WPAD 136   // ushort stride for LDS weight rows (272 B)
#define TP   136   // ushort stride for bf16 T rows (272 B)
#define MLPB 256   // persistent MLP blocks (1 per CU)
#define MLPW 16    // waves per MLP block (1024 thr): 4 waves/SIMD at 1 block/CU

__device__ __forceinline__ ushort f2bf(float f) {
    __hip_bfloat16 h = __float2bfloat16(f);   // RNE
    return __builtin_bit_cast(ushort, h);
}
__device__ __forceinline__ float bf2f(ushort u) {
    return __builtin_bit_cast(float, ((unsigned int)u) << 16);
}

// ===========================================================================
// CSR build via bucketed counting sort — ZERO global atomics. (proven R2/R7)
// ===========================================================================

__global__ void __launch_bounds__(256) bucket_hist(
    const int* __restrict__ dst, int* __restrict__ cnt)
{
    __shared__ int h[NBUCK];
    for (int i = threadIdx.x; i < NBUCK; i += 256) h[i] = 0;
    __syncthreads();
    int base = blockIdx.x * FCHUNK + threadIdx.x * EPT;
    if (base + EPT <= EE) {
        int4 d0 = *(const int4*)&dst[base];
        int4 d1 = *(const int4*)&dst[base + 4];
        int dd[8] = {d0.x, d0.y, d0.z, d0.w, d1.x, d1.y, d1.z, d1.w};
#pragma unroll
        for (int i = 0; i < 8; ++i) atomicAdd(&h[dd[i] >> WSHIFT], 1);
    } else {
        for (int i = 0; i < EPT; ++i) {
            int e = base + i;
            if (e < EE) atomicAdd(&h[dst[e] >> WSHIFT], 1);
        }
    }
    __syncthreads();
    for (int i = threadIdx.x; i < NBUCK; i += 256)
        cnt[i * NB_E + blockIdx.x] = h[i];
}

__global__ void __launch_bounds__(256) scan_cnt(
    int* __restrict__ cnt, int* __restrict__ total)
{
    __shared__ int wsum[4];
    int row = blockIdx.x;
    int* p = cnt + row * NB_E;
    int tid = threadIdx.x, lane = tid & 63, wid = tid >> 6;
    int v[4], s = 0;
#pragma unroll
    for (int j = 0; j < 4; ++j) {
        int idx = tid * 4 + j;
        v[j] = (idx < NB_E) ? p[idx] : 0;
        s += v[j];
    }
    int inc = s;
#pragma unroll
    for (int off = 1; off < 64; off <<= 1) {
        int n = __shfl_up(inc, off);
        if (lane >= off) inc += n;
    }
    if (lane == 63) wsum[wid] = inc;
    __syncthreads();
    int wofs = 0;
#pragma unroll
    for (int w = 0; w < 4; ++w)
        if (w < wid) wofs += wsum[w];
    int run = wofs + inc - s;
#pragma unroll
    for (int j = 0; j < 4; ++j) {
        int idx = tid * 4 + j;
        if (idx < NB_E) p[idx] = run;
        run += v[j];
    }
    if (tid == 255) total[row] = run;
}

__global__ void scan_base(const int* __restrict__ total,
                          int* __restrict__ bucketBase, int* __restrict__ rowptr)
{
    int lane = threadIdx.x;   // 64 threads
    int v[4], s = 0;
#pragma unroll
    for (int j = 0; j < 4; ++j) {
        int idx = lane * 4 + j;
        v[j] = (idx < NBUCK) ? total[idx] : 0;
        s += v[j];
    }
    int inc = s;
#pragma unroll
    for (int off = 1; off < 64; off <<= 1) {
        int n = __shfl_up(inc, off);
        if (lane >= off) inc += n;
    }
    int run = inc - s;
#pragma unroll
    for (int j = 0; j < 4; ++j) {
        int idx = lane * 4 + j;
        if (idx < NBUCK) bucketBase[idx] = run;
        run += v[j];
    }
    if (lane == 63) { bucketBase[NBUCK] = EE; rowptr[NN] = EE; }
}

__global__ void __launch_bounds__(256) bucket_scatter(
    const int* __restrict__ src, const int* __restrict__ dst,
    const int* __restrict__ cntEx, const int* __restrict__ bucketBase,
    unsigned int* __restrict__ pairs)
{
    __shared__ int h[NBUCK];
    __shared__ int bOfs[NBUCK];
    for (int i = threadIdx.x; i < NBUCK; i += 256) {
        h[i] = 0;
        bOfs[i] = bucketBase[i] + cntEx[i * NB_E + blockIdx.x];
    }
    __syncthreads();
    int base = blockIdx.x * FCHUNK + threadIdx.x * EPT;
    if (base + EPT <= EE) {
        int4 d0 = *(const int4*)&dst[base];
        int4 d1 = *(const int4*)&dst[base + 4];
        int4 s0 = *(const int4*)&src[base];
        int4 s1 = *(const int4*)&src[base + 4];
        int dd[8] = {d0.x, d0.y, d0.z, d0.w, d1.x, d1.y, d1.z, d1.w};
        int ss[8] = {s0.x, s0.y, s0.z, s0.w, s1.x, s1.y, s1.z, s1.w};
#pragma unroll
        for (int i = 0; i < 8; ++i) {
            int d = dd[i];
            int k = d >> WSHIFT;
            int r = atomicAdd(&h[k], 1);
            pairs[bOfs[k] + r] = ((unsigned)ss[i] << WSHIFT) | (unsigned)(d & (WB - 1));
        }
    } else {
        for (int i = 0; i < EPT; ++i) {
            int e = base + i;
            if (e < EE) {
                int d = dst[e];
                int k = d >> WSHIFT;
                int r = atomicAdd(&h[k], 1);
                pairs[bOfs[k] + r] = ((unsigned)src[e] << WSHIFT) | (unsigned)(d & (WB - 1));
            }
        }
    }
}

__global__ void __launch_bounds__(256) csr_build(
    const unsigned int* __restrict__ pairs, const int* __restrict__ bucketBase,
    int* __restrict__ rowptr, int* __restrict__ col)
{
    __shared__ int cnt[WB];
    __shared__ int ofs[WB];
    __shared__ int wsum[4];
    int k = blockIdx.x;
    int tid = threadIdx.x, lane = tid & 63, wid = tid >> 6;
    int nodeBase = k * WB;
    int nNodes = NN - nodeBase; if (nNodes > WB) nNodes = WB;
    for (int i = tid; i < WB; i += 256) cnt[i] = 0;
    __syncthreads();
    int beg = bucketBase[k], end = bucketBase[k + 1];
    for (int e = beg + tid; e < end; e += 256)
        atomicAdd(&cnt[pairs[e] & (WB - 1)], 1);
    __syncthreads();
    int a = cnt[2 * tid], b = cnt[2 * tid + 1];
    int s = a + b;
    int inc = s;
#pragma unroll
    for (int off = 1; off < 64; off <<= 1) {
        int n = __shfl_up(inc, off);
        if (lane >= off) inc += n;
    }
    if (lane == 63) wsum[wid] = inc;
    __syncthreads();
    int wofs = 0;
#pragma unroll
    for (int w = 0; w < 4; ++w)
        if (w < wid) wofs += wsum[w];
    int excl = wofs + inc - s;
    ofs[2 * tid] = excl;
    ofs[2 * tid + 1] = excl + a;
    __syncthreads();
    for (int i = tid; i < nNodes; i += 256)
        rowptr[nodeBase + i] = beg + ofs[i];
    __syncthreads();
    for (int e = beg + tid; e < end; e += 256) {
        unsigned p = pairs[e];
        int dl = p & (WB - 1);
        int r = atomicAdd(&ofs[dl], 1);
        col[beg + r] = (int)(p >> WSHIFT);
    }
}

// ===========================================================================
// Conversions — convert_x emits SLICE-MAJOR h (h[s][n][16 feats])
// ===========================================================================
__global__ void __launch_bounds__(256) convert_x_kernel(
    const float* __restrict__ x, ushort* __restrict__ xb)
{
    int t = blockIdx.x * 256 + threadIdx.x;   // NN*16 output 16B chunks
    int n = t >> 4;
    int c = t & 15;
    int s = c >> 1, h = c & 1;
    const float* xp = &x[n * CC + s * 16 + h * 8];
    f32x4 f0 = __builtin_nontemporal_load((const f32x4*)xp);
    f32x4 f1 = __builtin_nontemporal_load((const f32x4*)(xp + 4));
    bf16x8 o;
    o[0] = (short)f2bf(f0[0]); o[1] = (short)f2bf(f0[1]);
    o[2] = (short)f2bf(f0[2]); o[3] = (short)f2bf(f0[3]);
    o[4] = (short)f2bf(f1[0]); o[5] = (short)f2bf(f1[1]);
    o[6] = (short)f2bf(f1[2]); o[7] = (short)f2bf(f1[3]);
    *(bf16x8*)&xb[(size_t)s * SL + (size_t)n * 16 + h * 8] = o;
}

__global__ void __launch_bounds__(256) convert_w6_kernel(
    const float* __restrict__ w0, const float* __restrict__ w1,
    const float* __restrict__ w2, const float* __restrict__ w3,
    const float* __restrict__ w4, const float* __restrict__ w5,
    ushort* __restrict__ wt)
{
    int i = blockIdx.x * 256 + threadIdx.x;  // 6*16384
    int mat = i >> 14;
    int rem = i & 16383;
    int k = rem >> 7, n = rem & 127;
    const float* w = (mat == 0) ? w0 : (mat == 1) ? w1 : (mat == 2) ? w2
                   : (mat == 3) ? w3 : (mat == 4) ? w4 : w5;
    wt[mat * 16384 + n * 128 + k] = f2bf(w[k * 128 + n]);
}

// ===========================================================================
// Gather v3.1 — FEATURE-SLICED for XCD-L2 residency, with the CROSS-PAIR
// REDUCTION the v3 form was missing (R13 fail: each pair-lane wrote only
// its own 1/8 partial; absmax 0.51).
// Lane bits within 16-lane node group: bit0 = half (16B of 32B chunk),
// bits1-3 = pair (neighbor slot). After the neighbor loop, reduce partials
// across pair via __shfl_xor 2/4/8 (stays in-group), add self ONCE
// (post-reduction), and only pair==0 lanes store (2 lanes x 16B = chunk).
// ===========================================================================
__global__ void __launch_bounds__(256) gather_slice(
    const ushort* __restrict__ hs, const int* __restrict__ rowptr,
    const int* __restrict__ col, ushort* __restrict__ aggs)
{
    const int s     = blockIdx.x & (NSLICE - 1);
    const int nb    = blockIdx.x >> 3;
    const int grp   = threadIdx.x >> 4;             // 0..15 node in group
    const int l16   = threadIdx.x & 15;
    const int pair  = l16 >> 1;                     // 0..7 neighbor slot
    const int half  = l16 & 1;                      // 16B half of 32B slice
    const int gbase = (threadIdx.x & 63) & 48;      // group base lane in wave
    const int n = nb * 16 + grp;
    const ushort* base = hs + (size_t)s * SL;

    u16x8 self = *(const u16x8*)&base[(size_t)n * 16 + half * 8];
    float s0[8], s1[8];
#pragma unroll
    for (int k = 0; k < 8; ++k) { s0[k] = 0.f; s1[k] = 0.f; }

    int beg = __builtin_nontemporal_load(&rowptr[n]);
    int end = __builtin_nontemporal_load(&rowptr[n + 1]);
    while (beg < end) {
        int take = end - beg;
        if (take > 16) take = 16;
        int ci = (l16 < take) ? __builtin_nontemporal_load(&col[beg + l16]) : 0;
        int j = 0;
        for (; j + 16 <= take; j += 16) {
            int na = __shfl(ci, gbase + j + pair);
            int nbx = __shfl(ci, gbase + j + 8 + pair);
            u16x8 a0 = *(const u16x8*)&base[(size_t)na * 16 + half * 8];
            u16x8 a1 = *(const u16x8*)&base[(size_t)nbx * 16 + half * 8];
#pragma unroll
            for (int k = 0; k < 8; ++k) { s0[k] += bf2f(a0[k]); s1[k] += bf2f(a1[k]); }
        }
        for (; j + 8 <= take; j += 8) {
            int na = __shfl(ci, gbase + j + pair);
            u16x8 a0 = *(const u16x8*)&base[(size_t)na * 16 + half * 8];
#pragma unroll
            for (int k = 0; k < 8; ++k) s0[k] += bf2f(a0[k]);
        }
        if (j < take) {
            int m = take - j;                       // 1..7
            int idx = (pair < m) ? pair : 0;
            int na = __shfl(ci, gbase + j + idx);
            u16x8 a0 = *(const u16x8*)&base[(size_t)na * 16 + half * 8];
            if (pair < m) {
#pragma unroll
                for (int k = 0; k < 8; ++k) s0[k] += bf2f(a0[k]);
            }
        }
        beg += take;
    }

    // cross-pair reduction (bits 1..3 of l16); half-lanes hold distinct data
    float v[8];
#pragma unroll
    for (int k = 0; k < 8; ++k) {
        float t = s0[k] + s1[k];
        t += __shfl_xor(t, 2);
        t += __shfl_xor(t, 4);
        t += __shfl_xor(t, 8);
        v[k] = t + bf2f(self[k]);   // self added once, post-reduction
    }

    if (pair == 0) {
        bf16x8 o;
#pragma unroll
        for (int k = 0; k < 8; ++k) o[k] = (short)f2bf(v[k]);
        *(bf16x8*)&aggs[(size_t)s * SL + (size_t)n * 16 + half * 8] = o;
    }
}

// ===========================================================================
// MLP v9 (R11 proven: 24us/layer) with SLICE-MAJOR addressing.
//   input frag kk,quad -> slice 2kk+(quad>>1), ushort off (quad&1)*8
//   output chunk l16   -> slice l16>>1,        ushort off (l16&1)*8
// ===========================================================================
template <bool FUSE_HEAD>
__global__ void __launch_bounds__(1024, 2) mlp_persist(
    const ushort* __restrict__ hin,
    const ushort* __restrict__ waT, const float* __restrict__ ba,
    const ushort* __restrict__ wbT, const float* __restrict__ bb,
    ushort* __restrict__ hout,
    const float* __restrict__ lw, const float* __restrict__ lb,
    float* __restrict__ out)
{
    __shared__ ushort WaS[CC * WPAD];      // [n][k], row stride 136
    __shared__ ushort WbS[CC * WPAD];
    __shared__ ushort Tt[MLPW][16 * TP];   // per-wave bf16 T tile
    __shared__ float  baS[CC], bbS[CC], lwS[CC];

    const int tid = threadIdx.x;

    for (int i = tid; i < CC * 16; i += 1024) {        // 2 iters/thread
        int row = i >> 4, ch = i & 15;
        *(bf16x8*)&WaS[row * WPAD + ch * 8] = *(const bf16x8*)&waT[row * CC + ch * 8];
        *(bf16x8*)&WbS[row * WPAD + ch * 8] = *(const bf16x8*)&wbT[row * CC + ch * 8];
    }
    if (tid < CC)                       baS[tid]           = ba[tid];
    else if (tid < 2 * CC)              bbS[tid - CC]      = bb[tid - CC];
    else if (FUSE_HEAD && tid < 3 * CC) lwS[tid - 2 * CC]  = lw[tid - 2 * CC];
    __syncthreads();

    const int wave = tid >> 6;
    const int lane = tid & 63;
    const int quad = lane >> 4;
    const int l16  = lane & 15;
    ushort* T = Tt[wave];
    const int nTiles = NN / 16;            // 6250
    const int stride = MLPB * MLPW;        // 4096
    const int fq4 = quad * 4;
    float lbv = FUSE_HEAD ? lb[0] : 0.f;
    ushort* Trow = &T[l16 * TP];

    for (int wv = blockIdx.x * MLPW + wave; wv < nTiles; wv += stride) {
        const int wrow0 = wv * 16;

        // A fragments from slice-major hin
        bf16x8 af[4];
#pragma unroll
        for (int kk = 0; kk < 4; ++kk)
            af[kk] = *(const bf16x8*)&hin[(size_t)(2 * kk + (quad >> 1)) * SL
                                          + (size_t)(wrow0 + l16) * 16 + (quad & 1) * 8];

        // ---- stage 1 (swapped, nt-outer): one acc live at a time ----
#pragma unroll
        for (int nt = 0; nt < 8; ++nt) {
            f32x4 a = *(const f32x4*)&baS[nt * 16 + fq4];
#pragma unroll
            for (int kk = 0; kk < 4; ++kk) {
                bf16x8 wfrag = *(const bf16x8*)&WaS[(nt * 16 + l16) * WPAD + kk * 32 + quad * 8];
                a = __builtin_amdgcn_mfma_f32_16x16x32_bf16(wfrag, af[kk], a, 0, 0, 0);
            }
            ushort4 pk;
            pk.x = f2bf(fmaxf(a[0], 0.f));
            pk.y = f2bf(fmaxf(a[1], 0.f));
            pk.z = f2bf(fmaxf(a[2], 0.f));
            pk.w = f2bf(fmaxf(a[3], 0.f));
            *(ushort4*)&Trow[nt * 16 + fq4] = pk;   // retire immediately
        }
        __builtin_amdgcn_sched_barrier(0);

        // ---- stage-2 fragments: lane reads its own T row (b128) ----
        bf16x8 tf[4];
#pragma unroll
        for (int kk = 0; kk < 4; ++kk)
            tf[kk] = *(const bf16x8*)&Trow[kk * 32 + quad * 8];
        __builtin_amdgcn_sched_barrier(0);

        // ---- stage 2 (swapped, nt-outer) ----
        if (FUSE_HEAD) {
            float part = 0.f;
#pragma unroll
            for (int nt = 0; nt < 8; ++nt) {
                f32x4 a2 = *(const f32x4*)&bbS[nt * 16 + fq4];
#pragma unroll
                for (int kk = 0; kk < 4; ++kk) {
                    bf16x8 wfrag = *(const bf16x8*)&WbS[(nt * 16 + l16) * WPAD + kk * 32 + quad * 8];
                    a2 = __builtin_amdgcn_mfma_f32_16x16x32_bf16(wfrag, tf[kk], a2, 0, 0, 0);
                }
                f32x4 lw4 = *(const f32x4*)&lwS[nt * 16 + fq4];
#pragma unroll
                for (int r = 0; r < 4; ++r) {
                    float v = a2[r];
                    v = v > 0.f ? v : expm1f(v);
                    part += v * lw4[r];
                }
            }
            part += __shfl_xor(part, 16);
            part += __shfl_xor(part, 32);
            if (lane < 16) {
                float z = part + lbv;
                out[wrow0 + l16] = 1.f / (1.f + expf(-z));
            }
        } else {
#pragma unroll
            for (int nt = 0; nt < 8; ++nt) {
                f32x4 a2 = *(const f32x4*)&bbS[nt * 16 + fq4];
#pragma unroll
                for (int kk = 0; kk < 4; ++kk) {
                    bf16x8 wfrag = *(const bf16x8*)&WbS[(nt * 16 + l16) * WPAD + kk * 32 + quad * 8];
                    a2 = __builtin_amdgcn_mfma_f32_16x16x32_bf16(wfrag, tf[kk], a2, 0, 0, 0);
                }
                ushort4 pk;
#pragma unroll
                for (int r = 0; r < 4; ++r) {
                    float v = a2[r];
                    v = v > 0.f ? v : expm1f(v);
                    ((ushort*)&pk)[r] = f2bf(v);
                }
                *(ushort4*)&Trow[nt * 16 + fq4] = pk;
            }
            // slice-major 16B stores: full 128B lines (4 consec nodes x 32B)
#pragma unroll
            for (int i = 0; i < 4; ++i) {
                int r = i * 4 + quad;            // 0..15
                bf16x8 o = *(const bf16x8*)&T[r * TP + l16 * 8];
                *(bf16x8*)&hout[(size_t)(l16 >> 1) * SL
                                + (size_t)(wrow0 + r) * 16 + (l16 & 1) * 8] = o;
            }
        }
    }
}

extern "C" void kernel_launch(void* const* d_in, const int* in_sizes, int n_in,
                              void* d_out, int out_size, void* d_ws, size_t ws_size,
                              hipStream_t stream) {
    const float* x   = (const float*)d_in[0];
    const int*   ei  = (const int*)d_in[1];
    const int*   src = ei;
    const int*   dst = ei + EE;
    const float* w0a = (const float*)d_in[2];
    const float* b0a = (const float*)d_in[3];
    const float* w0b = (const float*)d_in[4];
    const float* b0b = (const float*)d_in[5];
    const float* w1a = (const float*)d_in[6];
    const float* b1a = (const float*)d_in[7];
    const float* w1b = (const float*)d_in[8];
    const float* b1b = (const float*)d_in[9];
    const float* w2a = (const float*)d_in[10];
    const float* b2a = (const float*)d_in[11];
    const float* w2b = (const float*)d_in[12];
    const float* b2b = (const float*)d_in[13];
    const float* lw  = (const float*)d_in[14];
    const float* lb  = (const float*)d_in[15];
    float* outp = (float*)d_out;

    // workspace layout (xb reused as layer-2 output); all h buffers slice-major
    ushort* xb  = (ushort*)d_ws;                      // N*CC bf16
    ushort* hbA = xb + (size_t)NN * CC;               // N*CC bf16
    ushort* agg = hbA + (size_t)NN * CC;              // N*CC bf16
    ushort* wT  = agg + (size_t)NN * CC;              // 6 * 128*128 bf16
    int* col    = (int*)(wT + 6 * CC * CC);           // EE
    int* rowptr = col + EE;                           // NN+1

    // CSR-build temporaries alias agg (dead until the first gather)
    unsigned int* pairs = (unsigned int*)agg;
    int* cnt        = (int*)(pairs + EE);
    int* total      = cnt + NBUCK * NB_E;
    int* bucketBase = total + NBUCK;                  // NBUCK+1

    ushort* w0aT = wT;
    ushort* w0bT = wT + 1 * CC * CC;
    ushort* w1aT = wT + 2 * CC * CC;
    ushort* w1bT = wT + 3 * CC * CC;
    ushort* w2aT = wT + 4 * CC * CC;
    ushort* w2bT = wT + 5 * CC * CC;

    const int gatherBlocks = (NN / 16) * NSLICE;      // 50000
    const int cvtXBlocks   = (NN * 16) / 256;         // 6250

    // ---- conversions ----
    convert_x_kernel<<<cvtXBlocks, 256, 0, stream>>>(x, xb);
    convert_w6_kernel<<<6 * 64, 256, 0, stream>>>(w0a, w0b, w1a, w1b, w2a, w2b, wT);

    // ---- CSR build (bucketed counting sort, no global atomics) ----
    bucket_hist<<<NCHUNKS, 256, 0, stream>>>(dst, cnt);
    scan_cnt<<<NBUCK, 256, 0, stream>>>(cnt, total);
    scan_base<<<1, 64, 0, stream>>>(total, bucketBase, rowptr);
    bucket_scatter<<<NCHUNKS, 256, 0, stream>>>(src, dst, cnt, bucketBase, pairs);
    csr_build<<<NBUCK, 256, 0, stream>>>(pairs, bucketBase, rowptr, col);

    // ---- layer 1 ----
    gather_slice<<<gatherBlocks, 256, 0, stream>>>(xb, rowptr, col, agg);
    mlp_persist<false><<<MLPB, 1024, 0, stream>>>(agg, w0aT, b0a, w0bT, b0b, hbA,
                                                  nullptr, nullptr, nullptr);
    // ---- layer 2 (output into xb) ----
    gather_slice<<<gatherBlocks, 256, 0, stream>>>(hbA, rowptr, col, agg);
    mlp_persist<false><<<MLPB, 1024, 0, stream>>>(agg, w1aT, b1a, w1bT, b1b, xb,
                                                  nullptr, nullptr, nullptr);
    // ---- layer 3 + fused head ----
    gather_slice<<<gatherBlocks, 256, 0, stream>>>(xb, rowptr, col, agg);
    mlp_persist<true><<<MLPB, 1024, 0, stream>>>(agg, w2aT, b2a, w2bT, b2b, nullptr,
                                                 lw, lb, outp);
}

// Round 16
// 412.762 us; speedup vs baseline: 1.4481x; 1.4481x over previous
//
#include <hip/hip_runtime.h>
#include <hip/hip_bf16.h>
#include <math.h>

#define NN 100000
#define CC 128
#define EE 1600000
#define EPT 8                    // edges per thread in edge-chunk kernels
#define FCHUNK (256 * EPT)       // 2048 edges per block
#define NCHUNKS ((EE + FCHUNK - 1) / FCHUNK)  // 782
#define NB_E NCHUNKS             // edge chunks
#define WB 512                   // nodes per bucket (power of 2)
#define WSHIFT 9
#define NBUCK ((NN + WB - 1) / WB)  // 196
#define XW (NN * CC / 4)         // 3,200,000 float4 x-chunks
#define WW (6 * 16384)           // 98,304 weight elements
#define CVT_B ((XW + WW) / 256)  // 12884 blocks exactly

typedef short  bf16x8 __attribute__((ext_vector_type(8)));
typedef float  f32x4  __attribute__((ext_vector_type(4)));
typedef unsigned short u16x8 __attribute__((ext_vector_type(8)));

#define WPAD 136   // ushort stride for LDS weight rows (272 B)
#define TP   136   // ushort stride for bf16 T rows (272 B)
#define MLPB 256   // persistent MLP blocks (1 per CU)
#define MLPW 16    // waves per MLP block (1024 thr): 4 waves/SIMD at 1 block/CU

__device__ __forceinline__ ushort f2bf(float f) {
    __hip_bfloat16 h = __float2bfloat16(f);   // RNE
    return __builtin_bit_cast(ushort, h);
}
__device__ __forceinline__ float bf2f(ushort u) {
    return __builtin_bit_cast(float, ((unsigned int)u) << 16);
}

// ===========================================================================
// convert_all — merges convert_x + convert_w6 (one dispatch instead of two).
// Also zeroes the `done` ticket used by scan_cnt_base.
// ===========================================================================
__global__ void __launch_bounds__(256) convert_all(
    const float* __restrict__ x, ushort* __restrict__ xb,
    const float* __restrict__ w0, const float* __restrict__ w1,
    const float* __restrict__ w2, const float* __restrict__ w3,
    const float* __restrict__ w4, const float* __restrict__ w5,
    ushort* __restrict__ wt, int* __restrict__ done)
{
    int i = blockIdx.x * 256 + threadIdx.x;
    if (i == 0) *done = 0;
    if (i < XW) {
        f32x4 v = __builtin_nontemporal_load((const f32x4*)x + i);
        ushort4 o;
        o.x = f2bf(v[0]); o.y = f2bf(v[1]); o.z = f2bf(v[2]); o.w = f2bf(v[3]);
        ((ushort4*)xb)[i] = o;
    } else {
        int j = i - XW;                       // < WW
        int mat = j >> 14, rem = j & 16383;
        int k = rem >> 7, n = rem & 127;
        const float* w = (mat == 0) ? w0 : (mat == 1) ? w1 : (mat == 2) ? w2
                       : (mat == 3) ? w3 : (mat == 4) ? w4 : w5;
        wt[mat * 16384 + n * 128 + k] = f2bf(w[k * 128 + n]);
    }
}

// ===========================================================================
// CSR build via bucketed counting sort — ZERO global atomics in the hot
// paths (proven R2/R7). scan_base is FOLDED into scan_cnt via the canonical
// last-block ticket (device-scope AGENT atomics, XCD-safe per G16) — one
// fewer dispatch than R11. R15 lesson: cooperative launch is NOT graph-safe
// in this harness; this pattern is.
// ===========================================================================

__global__ void __launch_bounds__(256) bucket_hist(
    const int* __restrict__ dst, int* __restrict__ cnt)
{
    __shared__ int h[NBUCK];
    for (int i = threadIdx.x; i < NBUCK; i += 256) h[i] = 0;
    __syncthreads();
    int base = blockIdx.x * FCHUNK + threadIdx.x * EPT;
    if (base + EPT <= EE) {
        int4 d0 = *(const int4*)&dst[base];
        int4 d1 = *(const int4*)&dst[base + 4];
        int dd[8] = {d0.x, d0.y, d0.z, d0.w, d1.x, d1.y, d1.z, d1.w};
#pragma unroll
        for (int i = 0; i < 8; ++i) atomicAdd(&h[dd[i] >> WSHIFT], 1);
    } else {
        for (int i = 0; i < EPT; ++i) {
            int e = base + i;
            if (e < EE) atomicAdd(&h[dst[e] >> WSHIFT], 1);
        }
    }
    __syncthreads();
    for (int i = threadIdx.x; i < NBUCK; i += 256)
        cnt[i * NB_E + blockIdx.x] = h[i];
}

__global__ void __launch_bounds__(256) scan_cnt_base(
    int* __restrict__ cnt, int* __restrict__ total, int* __restrict__ done,
    int* __restrict__ bucketBase, int* __restrict__ rowptr)
{
    __shared__ int wsum[4];
    __shared__ int isLast;
    int row = blockIdx.x;
    int* p = cnt + row * NB_E;
    int tid = threadIdx.x, lane = tid & 63, wid = tid >> 6;
    int v[4], s = 0;
#pragma unroll
    for (int j = 0; j < 4; ++j) {
        int idx = tid * 4 + j;
        v[j] = (idx < NB_E) ? p[idx] : 0;
        s += v[j];
    }
    int inc = s;
#pragma unroll
    for (int off = 1; off < 64; off <<= 1) {
        int n = __shfl_up(inc, off);
        if (lane >= off) inc += n;
    }
    if (lane == 63) wsum[wid] = inc;
    __syncthreads();
    int wofs = 0;
#pragma unroll
    for (int w = 0; w < 4; ++w)
        if (w < wid) wofs += wsum[w];
    int run = wofs + inc - s;
#pragma unroll
    for (int j = 0; j < 4; ++j) {
        int idx = tid * 4 + j;
        if (idx < NB_E) p[idx] = run;
        run += v[j];
    }
    // publish this bucket's total (device-scope release), take a ticket
    if (tid == 255) {
        __hip_atomic_store(&total[row], run, __ATOMIC_RELEASE,
                           __HIP_MEMORY_SCOPE_AGENT);
        int prev = __hip_atomic_fetch_add(done, 1, __ATOMIC_ACQ_REL,
                                          __HIP_MEMORY_SCOPE_AGENT);
        isLast = (prev == NBUCK - 1);
    }
    __syncthreads();
    // last block performs the base scan over all 196 totals
    if (isLast && tid < 64) {
        int bv[4], bs = 0;
#pragma unroll
        for (int j = 0; j < 4; ++j) {
            int idx = tid * 4 + j;
            bv[j] = (idx < NBUCK)
                  ? __hip_atomic_load(&total[idx], __ATOMIC_ACQUIRE,
                                      __HIP_MEMORY_SCOPE_AGENT)
                  : 0;
            bs += bv[j];
        }
        int binc = bs;
#pragma unroll
        for (int off = 1; off < 64; off <<= 1) {
            int n = __shfl_up(binc, off);
            if (tid >= off) binc += n;
        }
        int brun = binc - bs;
#pragma unroll
        for (int j = 0; j < 4; ++j) {
            int idx = tid * 4 + j;
            if (idx < NBUCK) bucketBase[idx] = brun;
            brun += bv[j];
        }
        if (tid == 63) { bucketBase[NBUCK] = EE; rowptr[NN] = EE; }
    }
}

__global__ void __launch_bounds__(256) bucket_scatter(
    const int* __restrict__ src, const int* __restrict__ dst,
    const int* __restrict__ cntEx, const int* __restrict__ bucketBase,
    unsigned int* __restrict__ pairs)
{
    __shared__ int h[NBUCK];
    __shared__ int bOfs[NBUCK];
    for (int i = threadIdx.x; i < NBUCK; i += 256) {
        h[i] = 0;
        bOfs[i] = bucketBase[i] + cntEx[i * NB_E + blockIdx.x];
    }
    __syncthreads();
    int base = blockIdx.x * FCHUNK + threadIdx.x * EPT;
    if (base + EPT <= EE) {
        int4 d0 = *(const int4*)&dst[base];
        int4 d1 = *(const int4*)&dst[base + 4];
        int4 s0 = *(const int4*)&src[base];
        int4 s1 = *(const int4*)&src[base + 4];
        int dd[8] = {d0.x, d0.y, d0.z, d0.w, d1.x, d1.y, d1.z, d1.w};
        int ss[8] = {s0.x, s0.y, s0.z, s0.w, s1.x, s1.y, s1.z, s1.w};
#pragma unroll
        for (int i = 0; i < 8; ++i) {
            int d = dd[i];
            int k = d >> WSHIFT;
            int r = atomicAdd(&h[k], 1);
            pairs[bOfs[k] + r] = ((unsigned)ss[i] << WSHIFT) | (unsigned)(d & (WB - 1));
        }
    } else {
        for (int i = 0; i < EPT; ++i) {
            int e = base + i;
            if (e < EE) {
                int d = dst[e];
                int k = d >> WSHIFT;
                int r = atomicAdd(&h[k], 1);
                pairs[bOfs[k] + r] = ((unsigned)src[e] << WSHIFT) | (unsigned)(d & (WB - 1));
            }
        }
    }
}

__global__ void __launch_bounds__(256) csr_build(
    const unsigned int* __restrict__ pairs, const int* __restrict__ bucketBase,
    int* __restrict__ rowptr, int* __restrict__ col)
{
    __shared__ int cnt[WB];
    __shared__ int ofs[WB];
    __shared__ int wsum[4];
    int k = blockIdx.x;
    int tid = threadIdx.x, lane = tid & 63, wid = tid >> 6;
    int nodeBase = k * WB;
    int nNodes = NN - nodeBase; if (nNodes > WB) nNodes = WB;
    for (int i = tid; i < WB; i += 256) cnt[i] = 0;
    __syncthreads();
    int beg = bucketBase[k], end = bucketBase[k + 1];
    for (int e = beg + tid; e < end; e += 256)
        atomicAdd(&cnt[pairs[e] & (WB - 1)], 1);
    __syncthreads();
    int a = cnt[2 * tid], b = cnt[2 * tid + 1];
    int s = a + b;
    int inc = s;
#pragma unroll
    for (int off = 1; off < 64; off <<= 1) {
        int n = __shfl_up(inc, off);
        if (lane >= off) inc += n;
    }
    if (lane == 63) wsum[wid] = inc;
    __syncthreads();
    int wofs = 0;
#pragma unroll
    for (int w = 0; w < 4; ++w)
        if (w < wid) wofs += wsum[w];
    int excl = wofs + inc - s;
    ofs[2 * tid] = excl;
    ofs[2 * tid + 1] = excl + a;
    __syncthreads();
    for (int i = tid; i < nNodes; i += 256)
        rowptr[nodeBase + i] = beg + ofs[i];
    __syncthreads();
    for (int e = beg + tid; e < end; e += 256) {
        unsigned p = pairs[e];
        int dl = p & (WB - 1);
        int r = atomicAdd(&ofs[dl], 1);
        col[beg + r] = (int)(p >> WSHIFT);
    }
}

// ===========================================================================
// Gather (R7/R11 proven row-major form: 4-deep ILP, VGPR 32, occ 68%,
// 60.3us). R9 (8-deep: slower) and R14 (L2-sliced: FETCH 188->46MB but 2.2x
// slower from 4x line-touches) both refuted — this is the service floor.
// ===========================================================================
__global__ void __launch_bounds__(256) gather_agg(
    const ushort* __restrict__ hin, const int* __restrict__ rowptr,
    const int* __restrict__ col, ushort* __restrict__ agg)
{
    const int grp    = threadIdx.x >> 4;            // 0..15
    const int lane16 = threadIdx.x & 15;
    const int gbase  = (threadIdx.x & 63) & 48;     // group base lane in wave
    const int n = blockIdx.x * 16 + grp;            // 6250*16 = 100000 exact
    const u16x8* hp = (const u16x8*)hin;

    u16x8 self = hp[n * 16 + lane16];
    float s0[8], s1[8], s2[8], s3[8];
#pragma unroll
    for (int k = 0; k < 8; ++k) {
        s0[k] = bf2f(self[k]); s1[k] = 0.f; s2[k] = 0.f; s3[k] = 0.f;
    }

    int beg = rowptr[n], end = rowptr[n + 1];
    while (beg < end) {
        int take = end - beg;
        if (take > 16) take = 16;
        int ci = (lane16 < take) ? col[beg + lane16] : 0;
        int j = 0;
        for (; j + 4 <= take; j += 4) {
            int n0 = __shfl(ci, gbase + j + 0);
            int n1 = __shfl(ci, gbase + j + 1);
            int n2 = __shfl(ci, gbase + j + 2);
            int n3 = __shfl(ci, gbase + j + 3);
            u16x8 a0 = hp[n0 * 16 + lane16];
            u16x8 a1 = hp[n1 * 16 + lane16];
            u16x8 a2 = hp[n2 * 16 + lane16];
            u16x8 a3 = hp[n3 * 16 + lane16];
#pragma unroll
            for (int k = 0; k < 8; ++k) {
                s0[k] += bf2f(a0[k]); s1[k] += bf2f(a1[k]);
                s2[k] += bf2f(a2[k]); s3[k] += bf2f(a3[k]);
            }
        }
        for (; j < take; ++j) {
            int n0 = __shfl(ci, gbase + j);
            u16x8 a0 = hp[n0 * 16 + lane16];
#pragma unroll
            for (int k = 0; k < 8; ++k) s0[k] += bf2f(a0[k]);
        }
        beg += take;
    }

    bf16x8 o;
#pragma unroll
    for (int k = 0; k < 8; ++k) o[k] = (short)f2bf(s0[k] + s1[k] + s2[k] + s3[k]);
    *(bf16x8*)&((ushort*)agg)[n * CC + lane16 * 8] = o;
}

// ===========================================================================
// MLP v9 (R11 proven, ~24us/layer): LDS-weight nt-outer single-acc swapped
// MFMA; 1024 thr / 16 waves share the 69.6KB staging; (1024,2) caps VGPR at
// 64 = proven natural demand; 4 waves/SIMD at 1 block/CU.
// ===========================================================================
template <bool FUSE_HEAD>
__global__ void __launch_bounds__(1024, 2) mlp_persist(
    const ushort* __restrict__ hin,
    const ushort* __restrict__ waT, const float* __restrict__ ba,
    const ushort* __restrict__ wbT, const float* __restrict__ bb,
    ushort* __restrict__ hout,
    const float* __restrict__ lw, const float* __restrict__ lb,
    float* __restrict__ out)
{
    __shared__ ushort WaS[CC * WPAD];      // [n][k], row stride 136
    __shared__ ushort WbS[CC * WPAD];
    __shared__ ushort Tt[MLPW][16 * TP];   // per-wave bf16 T tile
    __shared__ float  baS[CC], bbS[CC], lwS[CC];

    const int tid = threadIdx.x;

    for (int i = tid; i < CC * 16; i += 1024) {        // 2 iters/thread
        int row = i >> 4, ch = i & 15;
        *(bf16x8*)&WaS[row * WPAD + ch * 8] = *(const bf16x8*)&waT[row * CC + ch * 8];
        *(bf16x8*)&WbS[row * WPAD + ch * 8] = *(const bf16x8*)&wbT[row * CC + ch * 8];
    }
    if (tid < CC)                       baS[tid]           = ba[tid];
    else if (tid < 2 * CC)              bbS[tid - CC]      = bb[tid - CC];
    else if (FUSE_HEAD && tid < 3 * CC) lwS[tid - 2 * CC]  = lw[tid - 2 * CC];
    __syncthreads();

    const int wave = tid >> 6;
    const int lane = tid & 63;
    const int quad = lane >> 4;
    const int l16  = lane & 15;
    ushort* T = Tt[wave];
    const int nTiles = NN / 16;            // 6250
    const int stride = MLPB * MLPW;        // 4096
    const int fq4 = quad * 4;
    float lbv = FUSE_HEAD ? lb[0] : 0.f;
    ushort* Trow = &T[l16 * TP];

    for (int wv = blockIdx.x * MLPW + wave; wv < nTiles; wv += stride) {
        const int wrow0 = wv * 16;

        // A fragments (per-lane data doubles as B-frag of X^T)
        bf16x8 af[4];
#pragma unroll
        for (int kk = 0; kk < 4; ++kk)
            af[kk] = *(const bf16x8*)&hin[(wrow0 + l16) * CC + kk * 32 + quad * 8];

        // ---- stage 1 (swapped, nt-outer): one acc live at a time ----
#pragma unroll
        for (int nt = 0; nt < 8; ++nt) {
            f32x4 a = *(const f32x4*)&baS[nt * 16 + fq4];
#pragma unroll
            for (int kk = 0; kk < 4; ++kk) {
                bf16x8 wfrag = *(const bf16x8*)&WaS[(nt * 16 + l16) * WPAD + kk * 32 + quad * 8];
                a = __builtin_amdgcn_mfma_f32_16x16x32_bf16(wfrag, af[kk], a, 0, 0, 0);
            }
            ushort4 pk;
            pk.x = f2bf(fmaxf(a[0], 0.f));
            pk.y = f2bf(fmaxf(a[1], 0.f));
            pk.z = f2bf(fmaxf(a[2], 0.f));
            pk.w = f2bf(fmaxf(a[3], 0.f));
            *(ushort4*)&Trow[nt * 16 + fq4] = pk;   // retire immediately
        }
        __builtin_amdgcn_sched_barrier(0);

        // ---- stage-2 fragments: lane reads its own T row (b128) ----
        bf16x8 tf[4];
#pragma unroll
        for (int kk = 0; kk < 4; ++kk)
            tf[kk] = *(const bf16x8*)&Trow[kk * 32 + quad * 8];
        __builtin_amdgcn_sched_barrier(0);

        // ---- stage 2 (swapped, nt-outer) ----
        if (FUSE_HEAD) {
            float part = 0.f;
#pragma unroll
            for (int nt = 0; nt < 8; ++nt) {
                f32x4 a2 = *(const f32x4*)&bbS[nt * 16 + fq4];
#pragma unroll
                for (int kk = 0; kk < 4; ++kk) {
                    bf16x8 wfrag = *(const bf16x8*)&WbS[(nt * 16 + l16) * WPAD + kk * 32 + quad * 8];
                    a2 = __builtin_amdgcn_mfma_f32_16x16x32_bf16(wfrag, tf[kk], a2, 0, 0, 0);
                }
                f32x4 lw4 = *(const f32x4*)&lwS[nt * 16 + fq4];
#pragma unroll
                for (int r = 0; r < 4; ++r) {
                    float v = a2[r];
                    v = v > 0.f ? v : expm1f(v);
                    part += v * lw4[r];
                }
            }
            part += __shfl_xor(part, 16);
            part += __shfl_xor(part, 32);
            if (lane < 16) {
                float z = part + lbv;
                out[wrow0 + l16] = 1.f / (1.f + expf(-z));
            }
        } else {
#pragma unroll
            for (int nt = 0; nt < 8; ++nt) {
                f32x4 a2 = *(const f32x4*)&bbS[nt * 16 + fq4];
#pragma unroll
                for (int kk = 0; kk < 4; ++kk) {
                    bf16x8 wfrag = *(const bf16x8*)&WbS[(nt * 16 + l16) * WPAD + kk * 32 + quad * 8];
                    a2 = __builtin_amdgcn_mfma_f32_16x16x32_bf16(wfrag, tf[kk], a2, 0, 0, 0);
                }
                ushort4 pk;
#pragma unroll
                for (int r = 0; r < 4; ++r) {
                    float v = a2[r];
                    v = v > 0.f ? v : expm1f(v);
                    ((ushort*)&pk)[r] = f2bf(v);
                }
                *(ushort4*)&Trow[nt * 16 + fq4] = pk;
            }
            // coalesced 16B output stores (full-line writes)
#pragma unroll
            for (int i = 0; i < 4; ++i) {
                int r = i * 4 + quad;            // 0..15
                bf16x8 o = *(const bf16x8*)&T[r * TP + l16 * 8];
                *(bf16x8*)&hout[(wrow0 + r) * CC + l16 * 8] = o;
            }
        }
    }
}

extern "C" void kernel_launch(void* const* d_in, const int* in_sizes, int n_in,
                              void* d_out, int out_size, void* d_ws, size_t ws_size,
                              hipStream_t stream) {
    const float* x   = (const float*)d_in[0];
    const int*   ei  = (const int*)d_in[1];
    const int*   src = ei;
    const int*   dst = ei + EE;
    const float* w0a = (const float*)d_in[2];
    const float* b0a = (const float*)d_in[3];
    const float* w0b = (const float*)d_in[4];
    const float* b0b = (const float*)d_in[5];
    const float* w1a = (const float*)d_in[6];
    const float* b1a = (const float*)d_in[7];
    const float* w1b = (const float*)d_in[8];
    const float* b1b = (const float*)d_in[9];
    const float* w2a = (const float*)d_in[10];
    const float* b2a = (const float*)d_in[11];
    const float* w2b = (const float*)d_in[12];
    const float* b2b = (const float*)d_in[13];
    const float* lw  = (const float*)d_in[14];
    const float* lb  = (const float*)d_in[15];
    float* outp = (float*)d_out;

    // workspace layout (xb reused as layer-2 output)
    ushort* xb  = (ushort*)d_ws;                      // N*CC bf16
    ushort* hbA = xb + (size_t)NN * CC;               // N*CC bf16
    ushort* agg = hbA + (size_t)NN * CC;              // N*CC bf16
    ushort* wT  = agg + (size_t)NN * CC;              // 6 * 128*128 bf16
    int* col    = (int*)(wT + 6 * CC * CC);           // EE
    int* rowptr = col + EE;                           // NN+1

    // CSR-build temporaries alias agg (dead until the first gather)
    unsigned int* pairs = (unsigned int*)agg;
    int* cnt        = (int*)(pairs + EE);
    int* total      = cnt + NBUCK * NB_E;
    int* bucketBase = total + NBUCK;                  // NBUCK+1
    int* done       = bucketBase + NBUCK + 1;         // 1 (ticket)

    ushort* w0aT = wT;
    ushort* w0bT = wT + 1 * CC * CC;
    ushort* w1aT = wT + 2 * CC * CC;
    ushort* w1bT = wT + 3 * CC * CC;
    ushort* w2aT = wT + 4 * CC * CC;
    ushort* w2bT = wT + 5 * CC * CC;

    const int gatherBlocks = NN / 16;                 // 6250

    // ---- conversions (single dispatch; zeroes ticket) ----
    convert_all<<<CVT_B, 256, 0, stream>>>(x, xb, w0a, w0b, w1a, w1b, w2a, w2b,
                                           wT, done);

    // ---- CSR build (4 dispatches: hist, scan+base, scatter, build) ----
    bucket_hist<<<NB_E, 256, 0, stream>>>(dst, cnt);
    scan_cnt_base<<<NBUCK, 256, 0, stream>>>(cnt, total, done, bucketBase, rowptr);
    bucket_scatter<<<NB_E, 256, 0, stream>>>(src, dst, cnt, bucketBase, pairs);
    csr_build<<<NBUCK, 256, 0, stream>>>(pairs, bucketBase, rowptr, col);

    // ---- layer 1 ----
    gather_agg<<<gatherBlocks, 256, 0, stream>>>(xb, rowptr, col, agg);
    mlp_persist<false><<<MLPB, 1024, 0, stream>>>(agg, w0aT, b0a, w0bT, b0b, hbA,
                                                  nullptr, nullptr, nullptr);
    // ---- layer 2 (output into xb) ----
    gather_agg<<<gatherBlocks, 256, 0, stream>>>(hbA, rowptr, col, agg);
    mlp_persist<false><<<MLPB, 1024, 0, stream>>>(agg, w1aT, b1a, w1bT, b1b, xb,
                                                  nullptr, nullptr, nullptr);
    // ---- layer 3 + fused head ----
    gather_agg<<<gatherBlocks, 256, 0, stream>>>(xb, rowptr, col, agg);
    mlp_persist<true><<<MLPB, 1024, 0, stream>>>(agg, w2aT, b2a, w2bT, b2b, nullptr,
                                                 lw, lb, outp);
}

// Round 17
// 403.804 us; speedup vs baseline: 1.4802x; 1.0222x over previous
//
#include <hip/hip_runtime.h>
#include <hip/hip_bf16.h>
#include <math.h>

#define NN 100000
#define CC 128
#define EE 1600000
#define EPT 8                    // edges per thread in edge-chunk kernels
#define FCHUNK (256 * EPT)       // 2048 edges per block
#define NCHUNKS ((EE + FCHUNK - 1) / FCHUNK)  // 782
#define NB_E NCHUNKS             // edge chunks
#define WB 512                   // nodes per bucket (power of 2)
#define WSHIFT 9
#define NBUCK ((NN + WB - 1) / WB)  // 196

typedef short  bf16x8 __attribute__((ext_vector_type(8)));
typedef float  f32x4  __attribute__((ext_vector_type(4)));
typedef float  f32x4v __attribute__((ext_vector_type(4)));
typedef unsigned short u16x8 __attribute__((ext_vector_type(8)));

#define WPAD 136   // ushort stride for LDS weight rows (272 B)
#define TP   136   // ushort stride for bf16 T rows (272 B)
#define MLPB 256   // persistent MLP blocks (1 per CU)
#define MLPW 16    // waves per MLP block (1024 thr): 4 waves/SIMD at 1 block/CU

__device__ __forceinline__ ushort f2bf(float f) {
    __hip_bfloat16 h = __float2bfloat16(f);   // RNE
    return __builtin_bit_cast(ushort, h);
}
__device__ __forceinline__ float bf2f(ushort u) {
    return __builtin_bit_cast(float, ((unsigned int)u) << 16);
}

// ===========================================================================
// CSR build via bucketed counting sort — ZERO global atomics. (proven R2/R7)
// ===========================================================================

__global__ void __launch_bounds__(256) bucket_hist(
    const int* __restrict__ dst, int* __restrict__ cnt)
{
    __shared__ int h[NBUCK];
    for (int i = threadIdx.x; i < NBUCK; i += 256) h[i] = 0;
    __syncthreads();
    int base = blockIdx.x * FCHUNK + threadIdx.x * EPT;
    if (base + EPT <= EE) {
        int4 d0 = *(const int4*)&dst[base];
        int4 d1 = *(const int4*)&dst[base + 4];
        int dd[8] = {d0.x, d0.y, d0.z, d0.w, d1.x, d1.y, d1.z, d1.w};
#pragma unroll
        for (int i = 0; i < 8; ++i) atomicAdd(&h[dd[i] >> WSHIFT], 1);
    } else {
        for (int i = 0; i < EPT; ++i) {
            int e = base + i;
            if (e < EE) atomicAdd(&h[dst[e] >> WSHIFT], 1);
        }
    }
    __syncthreads();
    for (int i = threadIdx.x; i < NBUCK; i += 256)
        cnt[i * NB_E + blockIdx.x] = h[i];
}

__global__ void __launch_bounds__(256) scan_cnt(
    int* __restrict__ cnt, int* __restrict__ total)
{
    __shared__ int wsum[4];
    int row = blockIdx.x;
    int* p = cnt + row * NB_E;
    int tid = threadIdx.x, lane = tid & 63, wid = tid >> 6;
    int v[4], s = 0;
#pragma unroll
    for (int j = 0; j < 4; ++j) {
        int idx = tid * 4 + j;
        v[j] = (idx < NB_E) ? p[idx] : 0;
        s += v[j];
    }
    int inc = s;
#pragma unroll
    for (int off = 1; off < 64; off <<= 1) {
        int n = __shfl_up(inc, off);
        if (lane >= off) inc += n;
    }
    if (lane == 63) wsum[wid] = inc;
    __syncthreads();
    int wofs = 0;
#pragma unroll
    for (int w = 0; w < 4; ++w)
        if (w < wid) wofs += wsum[w];
    int run = wofs + inc - s;
#pragma unroll
    for (int j = 0; j < 4; ++j) {
        int idx = tid * 4 + j;
        if (idx < NB_E) p[idx] = run;
        run += v[j];
    }
    if (tid == 255) total[row] = run;
}

__global__ void scan_base(const int* __restrict__ total,
                          int* __restrict__ bucketBase, int* __restrict__ rowptr)
{
    int lane = threadIdx.x;   // 64 threads
    int v[4], s = 0;
#pragma unroll
    for (int j = 0; j < 4; ++j) {
        int idx = lane * 4 + j;
        v[j] = (idx < NBUCK) ? total[idx] : 0;
        s += v[j];
    }
    int inc = s;
#pragma unroll
    for (int off = 1; off < 64; off <<= 1) {
        int n = __shfl_up(inc, off);
        if (lane >= off) inc += n;
    }
    int run = inc - s;
#pragma unroll
    for (int j = 0; j < 4; ++j) {
        int idx = lane * 4 + j;
        if (idx < NBUCK) bucketBase[idx] = run;
        run += v[j];
    }
    if (lane == 63) { bucketBase[NBUCK] = EE; rowptr[NN] = EE; }
}

__global__ void __launch_bounds__(256) bucket_scatter(
    const int* __restrict__ src, const int* __restrict__ dst,
    const int* __restrict__ cntEx, const int* __restrict__ bucketBase,
    unsigned int* __restrict__ pairs)
{
    __shared__ int h[NBUCK];
    __shared__ int bOfs[NBUCK];
    for (int i = threadIdx.x; i < NBUCK; i += 256) {
        h[i] = 0;
        bOfs[i] = bucketBase[i] + cntEx[i * NB_E + blockIdx.x];
    }
    __syncthreads();
    int base = blockIdx.x * FCHUNK + threadIdx.x * EPT;
    if (base + EPT <= EE) {
        int4 d0 = *(const int4*)&dst[base];
        int4 d1 = *(const int4*)&dst[base + 4];
        int4 s0 = *(const int4*)&src[base];
        int4 s1 = *(const int4*)&src[base + 4];
        int dd[8] = {d0.x, d0.y, d0.z, d0.w, d1.x, d1.y, d1.z, d1.w};
        int ss[8] = {s0.x, s0.y, s0.z, s0.w, s1.x, s1.y, s1.z, s1.w};
#pragma unroll
        for (int i = 0; i < 8; ++i) {
            int d = dd[i];
            int k = d >> WSHIFT;
            int r = atomicAdd(&h[k], 1);
            pairs[bOfs[k] + r] = ((unsigned)ss[i] << WSHIFT) | (unsigned)(d & (WB - 1));
        }
    } else {
        for (int i = 0; i < EPT; ++i) {
            int e = base + i;
            if (e < EE) {
                int d = dst[e];
                int k = d >> WSHIFT;
                int r = atomicAdd(&h[k], 1);
                pairs[bOfs[k] + r] = ((unsigned)src[e] << WSHIFT) | (unsigned)(d & (WB - 1));
            }
        }
    }
}

__global__ void __launch_bounds__(256) csr_build(
    const unsigned int* __restrict__ pairs, const int* __restrict__ bucketBase,
    int* __restrict__ rowptr, int* __restrict__ col)
{
    __shared__ int cnt[WB];
    __shared__ int ofs[WB];
    __shared__ int wsum[4];
    int k = blockIdx.x;
    int tid = threadIdx.x, lane = tid & 63, wid = tid >> 6;
    int nodeBase = k * WB;
    int nNodes = NN - nodeBase; if (nNodes > WB) nNodes = WB;
    for (int i = tid; i < WB; i += 256) cnt[i] = 0;
    __syncthreads();
    int beg = bucketBase[k], end = bucketBase[k + 1];
    for (int e = beg + tid; e < end; e += 256)
        atomicAdd(&cnt[pairs[e] & (WB - 1)], 1);
    __syncthreads();
    int a = cnt[2 * tid], b = cnt[2 * tid + 1];
    int s = a + b;
    int inc = s;
#pragma unroll
    for (int off = 1; off < 64; off <<= 1) {
        int n = __shfl_up(inc, off);
        if (lane >= off) inc += n;
    }
    if (lane == 63) wsum[wid] = inc;
    __syncthreads();
    int wofs = 0;
#pragma unroll
    for (int w = 0; w < 4; ++w)
        if (w < wid) wofs += wsum[w];
    int excl = wofs + inc - s;
    ofs[2 * tid] = excl;
    ofs[2 * tid + 1] = excl + a;
    __syncthreads();
    for (int i = tid; i < nNodes; i += 256)
        rowptr[nodeBase + i] = beg + ofs[i];
    __syncthreads();
    for (int e = beg + tid; e < end; e += 256) {
        unsigned p = pairs[e];
        int dl = p & (WB - 1);
        int r = atomicAdd(&ofs[dl], 1);
        col[beg + r] = (int)(p >> WSHIFT);
    }
}

// ===========================================================================
// Conversions
// ===========================================================================
__global__ void __launch_bounds__(256) convert_x_kernel(
    const float* __restrict__ x, ushort* __restrict__ xb)
{
    int i = blockIdx.x * 256 + threadIdx.x;   // float4 groups; NN*CC/4 total
    f32x4v v = __builtin_nontemporal_load((const f32x4v*)x + i);
    ushort4 o;
    o.x = f2bf(v[0]); o.y = f2bf(v[1]); o.z = f2bf(v[2]); o.w = f2bf(v[3]);
    ((ushort4*)xb)[i] = o;
}

__global__ void __launch_bounds__(256) convert_w6_kernel(
    const float* __restrict__ w0, const float* __restrict__ w1,
    const float* __restrict__ w2, const float* __restrict__ w3,
    const float* __restrict__ w4, const float* __restrict__ w5,
    ushort* __restrict__ wt)
{
    int i = blockIdx.x * 256 + threadIdx.x;  // 6*16384
    int mat = i >> 14;
    int rem = i & 16383;
    int k = rem >> 7, n = rem & 127;
    const float* w = (mat == 0) ? w0 : (mat == 1) ? w1 : (mat == 2) ? w2
                   : (mat == 3) ? w3 : (mat == 4) ? w4 : w5;
    wt[mat * 16384 + n * 128 + k] = f2bf(w[k * 128 + n]);
}

// ===========================================================================
// Gather (R7 proven form: 4-deep ILP, VGPR 32, occ 68%, 60.3us). At the
// 8-XCD service floor (FETCH ~188MB = 8 x 25.6MB table); alternatives
// refuted: 8-deep ILP (R9), L2-slice layout (R14), gather+MLP fusion (R8).
// ===========================================================================
__global__ void __launch_bounds__(256) gather_agg(
    const ushort* __restrict__ hin, const int* __restrict__ rowptr,
    const int* __restrict__ col, ushort* __restrict__ agg)
{
    const int grp    = threadIdx.x >> 4;            // 0..15
    const int lane16 = threadIdx.x & 15;
    const int gbase  = (threadIdx.x & 63) & 48;     // group base lane in wave
    const int n = blockIdx.x * 16 + grp;            // 6250*16 = 100000 exact
    const u16x8* hp = (const u16x8*)hin;

    u16x8 self = hp[n * 16 + lane16];
    float s0[8], s1[8], s2[8], s3[8];
#pragma unroll
    for (int k = 0; k < 8; ++k) {
        s0[k] = bf2f(self[k]); s1[k] = 0.f; s2[k] = 0.f; s3[k] = 0.f;
    }

    int beg = rowptr[n], end = rowptr[n + 1];
    while (beg < end) {
        int take = end - beg;
        if (take > 16) take = 16;
        int ci = (lane16 < take) ? col[beg + lane16] : 0;
        int j = 0;
        for (; j + 4 <= take; j += 4) {
            int n0 = __shfl(ci, gbase + j + 0);
            int n1 = __shfl(ci, gbase + j + 1);
            int n2 = __shfl(ci, gbase + j + 2);
            int n3 = __shfl(ci, gbase + j + 3);
            u16x8 a0 = hp[n0 * 16 + lane16];
            u16x8 a1 = hp[n1 * 16 + lane16];
            u16x8 a2 = hp[n2 * 16 + lane16];
            u16x8 a3 = hp[n3 * 16 + lane16];
#pragma unroll
            for (int k = 0; k < 8; ++k) {
                s0[k] += bf2f(a0[k]); s1[k] += bf2f(a1[k]);
                s2[k] += bf2f(a2[k]); s3[k] += bf2f(a3[k]);
            }
        }
        for (; j < take; ++j) {
            int n0 = __shfl(ci, gbase + j);
            u16x8 a0 = hp[n0 * 16 + lane16];
#pragma unroll
            for (int k = 0; k < 8; ++k) s0[k] += bf2f(a0[k]);
        }
        beg += take;
    }

    bf16x8 o;
#pragma unroll
    for (int k = 0; k < 8; ++k) o[k] = (short)f2bf(s0[k] + s1[k] + s2[k] + s3[k]);
    *(bf16x8*)&((ushort*)agg)[n * CC + lane16 * 8] = o;
}

// ===========================================================================
// MLP v9 (R11 proven, ~24us/layer): LDS-weight nt-outer single-acc swapped
// MFMA; 1024 thr / 16 waves share the 69.6KB staging; (1024,2) caps VGPR at
// 64 = proven natural demand; 4 waves/SIMD at 1 block/CU.
// ===========================================================================
template <bool FUSE_HEAD>
__global__ void __launch_bounds__(1024, 2) mlp_persist(
    const ushort* __restrict__ hin,
    const ushort* __restrict__ waT, const float* __restrict__ ba,
    const ushort* __restrict__ wbT, const float* __restrict__ bb,
    ushort* __restrict__ hout,
    const float* __restrict__ lw, const float* __restrict__ lb,
    float* __restrict__ out)
{
    __shared__ ushort WaS[CC * WPAD];      // [n][k], row stride 136
    __shared__ ushort WbS[CC * WPAD];
    __shared__ ushort Tt[MLPW][16 * TP];   // per-wave bf16 T tile
    __shared__ float  baS[CC], bbS[CC], lwS[CC];

    const int tid = threadIdx.x;

    for (int i = tid; i < CC * 16; i += 1024) {        // 2 iters/thread
        int row = i >> 4, ch = i & 15;
        *(bf16x8*)&WaS[row * WPAD + ch * 8] = *(const bf16x8*)&waT[row * CC + ch * 8];
        *(bf16x8*)&WbS[row * WPAD + ch * 8] = *(const bf16x8*)&wbT[row * CC + ch * 8];
    }
    if (tid < CC)                       baS[tid]           = ba[tid];
    else if (tid < 2 * CC)              bbS[tid - CC]      = bb[tid - CC];
    else if (FUSE_HEAD && tid < 3 * CC) lwS[tid - 2 * CC]  = lw[tid - 2 * CC];
    __syncthreads();

    const int wave = tid >> 6;
    const int lane = tid & 63;
    const int quad = lane >> 4;
    const int l16  = lane & 15;
    ushort* T = Tt[wave];
    const int nTiles = NN / 16;            // 6250
    const int stride = MLPB * MLPW;        // 4096
    const int fq4 = quad * 4;
    float lbv = FUSE_HEAD ? lb[0] : 0.f;
    ushort* Trow = &T[l16 * TP];

    for (int wv = blockIdx.x * MLPW + wave; wv < nTiles; wv += stride) {
        const int wrow0 = wv * 16;

        // A fragments (per-lane data doubles as B-frag of X^T)
        bf16x8 af[4];
#pragma unroll
        for (int kk = 0; kk < 4; ++kk)
            af[kk] = *(const bf16x8*)&hin[(wrow0 + l16) * CC + kk * 32 + quad * 8];

        // ---- stage 1 (swapped, nt-outer): one acc live at a time ----
#pragma unroll
        for (int nt = 0; nt < 8; ++nt) {
            f32x4 a = *(const f32x4*)&baS[nt * 16 + fq4];
#pragma unroll
            for (int kk = 0; kk < 4; ++kk) {
                bf16x8 wfrag = *(const bf16x8*)&WaS[(nt * 16 + l16) * WPAD + kk * 32 + quad * 8];
                a = __builtin_amdgcn_mfma_f32_16x16x32_bf16(wfrag, af[kk], a, 0, 0, 0);
            }
            ushort4 pk;
            pk.x = f2bf(fmaxf(a[0], 0.f));
            pk.y = f2bf(fmaxf(a[1], 0.f));
            pk.z = f2bf(fmaxf(a[2], 0.f));
            pk.w = f2bf(fmaxf(a[3], 0.f));
            *(ushort4*)&Trow[nt * 16 + fq4] = pk;   // retire immediately
        }
        __builtin_amdgcn_sched_barrier(0);

        // ---- stage-2 fragments: lane reads its own T row (b128) ----
        bf16x8 tf[4];
#pragma unroll
        for (int kk = 0; kk < 4; ++kk)
            tf[kk] = *(const bf16x8*)&Trow[kk * 32 + quad * 8];
        __builtin_amdgcn_sched_barrier(0);

        // ---- stage 2 (swapped, nt-outer) ----
        if (FUSE_HEAD) {
            float part = 0.f;
#pragma unroll
            for (int nt = 0; nt < 8; ++nt) {
                f32x4 a2 = *(const f32x4*)&bbS[nt * 16 + fq4];
#pragma unroll
                for (int kk = 0; kk < 4; ++kk) {
                    bf16x8 wfrag = *(const bf16x8*)&WbS[(nt * 16 + l16) * WPAD + kk * 32 + quad * 8];
                    a2 = __builtin_amdgcn_mfma_f32_16x16x32_bf16(wfrag, tf[kk], a2, 0, 0, 0);
                }
                f32x4 lw4 = *(const f32x4*)&lwS[nt * 16 + fq4];
#pragma unroll
                for (int r = 0; r < 4; ++r) {
                    float v = a2[r];
                    v = v > 0.f ? v : expm1f(v);
                    part += v * lw4[r];
                }
            }
            part += __shfl_xor(part, 16);
            part += __shfl_xor(part, 32);
            if (lane < 16) {
                float z = part + lbv;
                out[wrow0 + l16] = 1.f / (1.f + expf(-z));
            }
        } else {
#pragma unroll
            for (int nt = 0; nt < 8; ++nt) {
                f32x4 a2 = *(const f32x4*)&bbS[nt * 16 + fq4];
#pragma unroll
                for (int kk = 0; kk < 4; ++kk) {
                    bf16x8 wfrag = *(const bf16x8*)&WbS[(nt * 16 + l16) * WPAD + kk * 32 + quad * 8];
                    a2 = __builtin_amdgcn_mfma_f32_16x16x32_bf16(wfrag, tf[kk], a2, 0, 0, 0);
                }
                ushort4 pk;
#pragma unroll
                for (int r = 0; r < 4; ++r) {
                    float v = a2[r];
                    v = v > 0.f ? v : expm1f(v);
                    ((ushort*)&pk)[r] = f2bf(v);
                }
                *(ushort4*)&Trow[nt * 16 + fq4] = pk;
            }
            // coalesced 16B output stores (full-line writes)
#pragma unroll
            for (int i = 0; i < 4; ++i) {
                int r = i * 4 + quad;            // 0..15
                bf16x8 o = *(const bf16x8*)&T[r * TP + l16 * 8];
                *(bf16x8*)&hout[(wrow0 + r) * CC + l16 * 8] = o;
            }
        }
    }
}

extern "C" void kernel_launch(void* const* d_in, const int* in_sizes, int n_in,
                              void* d_out, int out_size, void* d_ws, size_t ws_size,
                              hipStream_t stream) {
    const float* x   = (const float*)d_in[0];
    const int*   ei  = (const int*)d_in[1];
    const int*   src = ei;
    const int*   dst = ei + EE;
    const float* w0a = (const float*)d_in[2];
    const float* b0a = (const float*)d_in[3];
    const float* w0b = (const float*)d_in[4];
    const float* b0b = (const float*)d_in[5];
    const float* w1a = (const float*)d_in[6];
    const float* b1a = (const float*)d_in[7];
    const float* w1b = (const float*)d_in[8];
    const float* b1b = (const float*)d_in[9];
    const float* w2a = (const float*)d_in[10];
    const float* b2a = (const float*)d_in[11];
    const float* w2b = (const float*)d_in[12];
    const float* b2b = (const float*)d_in[13];
    const float* lw  = (const float*)d_in[14];
    const float* lb  = (const float*)d_in[15];
    float* outp = (float*)d_out;

    // workspace layout (xb reused as layer-2 output)
    ushort* xb  = (ushort*)d_ws;                      // N*CC bf16
    ushort* hbA = xb + (size_t)NN * CC;               // N*CC bf16
    ushort* agg = hbA + (size_t)NN * CC;              // N*CC bf16
    ushort* wT  = agg + (size_t)NN * CC;              // 6 * 128*128 bf16
    int* col    = (int*)(wT + 6 * CC * CC);           // EE
    int* rowptr = col + EE;                           // NN+1

    // CSR-build temporaries alias agg (dead until the first gather)
    unsigned int* pairs = (unsigned int*)agg;
    int* cnt        = (int*)(pairs + EE);
    int* total      = cnt + NBUCK * NB_E;
    int* bucketBase = total + NBUCK;                  // NBUCK+1

    ushort* w0aT = wT;
    ushort* w0bT = wT + 1 * CC * CC;
    ushort* w1aT = wT + 2 * CC * CC;
    ushort* w1bT = wT + 3 * CC * CC;
    ushort* w2aT = wT + 4 * CC * CC;
    ushort* w2bT = wT + 5 * CC * CC;

    const int gatherBlocks = NN / 16;                 // 6250
    const int cvtXBlocks   = (NN * CC / 4) / 256;     // 12500

    // ---- conversions ----
    convert_x_kernel<<<cvtXBlocks, 256, 0, stream>>>(x, xb);
    convert_w6_kernel<<<6 * 64, 256, 0, stream>>>(w0a, w0b, w1a, w1b, w2a, w2b, wT);

    // ---- CSR build (bucketed counting sort, no global atomics) ----
    bucket_hist<<<NB_E, 256, 0, stream>>>(dst, cnt);
    scan_cnt<<<NBUCK, 256, 0, stream>>>(cnt, total);
    scan_base<<<1, 64, 0, stream>>>(total, bucketBase, rowptr);
    bucket_scatter<<<NB_E, 256, 0, stream>>>(src, dst, cnt, bucketBase, pairs);
    csr_build<<<NBUCK, 256, 0, stream>>>(pairs, bucketBase, rowptr, col);

    // ---- layer 1 ----
    gather_agg<<<gatherBlocks, 256, 0, stream>>>(xb, rowptr, col, agg);
    mlp_persist<false><<<MLPB, 1024, 0, stream>>>(agg, w0aT, b0a, w0bT, b0b, hbA,
                                                  nullptr, nullptr, nullptr);
    // ---- layer 2 (output into xb) ----
    gather_agg<<<gatherBlocks, 256, 0, stream>>>(hbA, rowptr, col, agg);
    mlp_persist<false><<<MLPB, 1024, 0, stream>>>(agg, w1aT, b1a, w1bT, b1b, xb,
                                                  nullptr, nullptr, nullptr);
    // ---- layer 3 + fused head ----
    gather_agg<<<gatherBlocks, 256, 0, stream>>>(xb, rowptr, col, agg);
    mlp_persist<true><<<MLPB, 1024, 0, stream>>>(agg, w2aT, b2a, w2bT, b2b, nullptr,
                                                 lw, lb, outp);
}